// Round 22
// baseline (306.252 us; speedup 1.0000x reference)
//
#include <hip/hip_runtime.h>

#define F_IN 165
#define KP_PROJ 168
constexpr float NEG_SLOPE = 0.2f;

// lrelu(z) = max(z, 0.2z) -- 2 VALU inst vs 3 for cmp/cndmask form.
__device__ __forceinline__ float lrelu(float z) { return fmaxf(z, NEG_SLOPE * z); }

// ---- weight transposes + va vectors + workspace zeroing ---------------------
__global__ void k_trans(const float* __restrict__ pw, const float* __restrict__ w2,
                        const float* __restrict__ w1, const float* __restrict__ as1w,
                        const float* __restrict__ ad1w,
                        float* __restrict__ t0, float* __restrict__ t2,
                        float* __restrict__ va, int* __restrict__ dc, int ndc) {
    int i = blockIdx.x * 256 + threadIdx.x;
    const int n0 = 64 * KP_PROJ, n2 = 64 * 256;
    if (i < n0) {
        int c = i / KP_PROJ, r = i - c * KP_PROJ;
        t0[i] = (r < F_IN) ? pw[r * 64 + c] : 0.f;
    } else if (i < n0 + n2) {
        int j = i - n0; int c = j >> 8, r = j & 255;
        t2[j] = w2[r * 64 + c];
    } else if (i < n0 + n2 + 512) {
        int j = i - n0 - n2;          // 0..511
        int i2 = j >> 6;              // 0..7 = plane*4 + h
        int plane = i2 >> 2, h = i2 & 3, k = j & 63;
        const float* att = plane ? ad1w : as1w;
        float acc = 0.f;
        for (int c = 0; c < 64; ++c)
            acc = fmaf(w1[k * 256 + h * 64 + c], att[h * 64 + c], acc);
        va[j] = acc;
    }
    int z = i - (n0 + n2 + 512);
    if (z >= 0 && z < ndc) dc[z] = 0;
}

// ---- h0 = relu(x @ W + b) + fused as1/ad1 via single-wave LDS transpose -----
__global__ void k_proj(const float* __restrict__ x, const float* __restrict__ Wt,
                       const float* __restrict__ b, const float* __restrict__ va,
                       float* __restrict__ h0, float* __restrict__ as_,
                       float* __restrict__ ad_, int N) {
    __shared__ float xs[32][KP_PROJ];
    __shared__ float vas[8][65];
    __shared__ float hrow[4][64];
    int base = blockIdx.x * 32;
    int t = threadIdx.x;
    for (int idx = t; idx < 512; idx += 256)
        vas[idx >> 6][idx & 63] = va[idx];
    for (int idx = t; idx < 32 * KP_PROJ; idx += 256) {
        int nl = idx / KP_PROJ, k = idx - nl * KP_PROJ;
        int node = base + nl;
        xs[nl][k] = (node < N && k < F_IN) ? x[(size_t)node * F_IN + k] : 0.f;
    }
    __syncthreads();
    int g = t >> 6, col = t & 63;
    float acc[8];
    float bb = b[col];
#pragma unroll
    for (int m = 0; m < 8; ++m) acc[m] = bb;
    const float* wrow = Wt + col * KP_PROJ;
    for (int k4 = 0; k4 < KP_PROJ / 4; ++k4) {
        float4 wv = *(const float4*)(wrow + k4 * 4);
#pragma unroll
        for (int m = 0; m < 8; ++m) {
            float4 av = *(const float4*)&xs[g * 8 + m][k4 * 4];
            acc[m] = fmaf(av.x, wv.x, acc[m]);
            acc[m] = fmaf(av.y, wv.y, acc[m]);
            acc[m] = fmaf(av.z, wv.z, acc[m]);
            acc[m] = fmaf(av.w, wv.w, acc[m]);
        }
    }
    int i8 = col & 7, c8 = col >> 3;
    const float* vbase = &vas[i8][c8 * 8];
    const float* hbase = &hrow[g][c8 * 8];
#pragma unroll
    for (int m = 0; m < 8; ++m) {
        int node = base + g * 8 + m;
        float h = fmaxf(acc[m], 0.f);
        if (node < N) h0[(size_t)node * 64 + col] = h;
        hrow[g][col] = h;            // wave-private LDS, wave-synchronous use
        float r = 0.f;
#pragma unroll
        for (int e = 0; e < 8; ++e)
            r = fmaf(hbase[e], vbase[e], r);
        r += __shfl_xor(r, 8, 64);
        r += __shfl_xor(r, 16, 64);
        r += __shfl_xor(r, 32, 64);
        if (node < N && col < 8) {
            if (col < 4) as_[(size_t)node * 4 + col] = r;
            else         ad_[(size_t)node * 4 + (col - 4)] = r;
        }
    }
}

// ---- h2lin = h1 @ W2: Wt2[64][256], 32 nodes/block, 4 groups x 8, fused att -
__global__ void k_lin2(const float* __restrict__ h1, const float* __restrict__ Wt,
                       const float* __restrict__ att_s, const float* __restrict__ att_d,
                       float* __restrict__ out, float* __restrict__ as_,
                       float* __restrict__ ad_, int N) {
    __shared__ float hs[32][256];
    int base = blockIdx.x * 32;
    int t = threadIdx.x;
    for (int i = 0; i < 8; ++i) {
        int idx4 = t + i * 256;
        int nl = idx4 >> 6, k4 = idx4 & 63;
        int node = base + nl;
        float4 v = make_float4(0.f, 0.f, 0.f, 0.f);
        if (node < N) v = *(const float4*)(h1 + (size_t)node * 256 + k4 * 4);
        *(float4*)&hs[nl][k4 * 4] = v;
    }
    __syncthreads();
    int g = t >> 6, col = t & 63;
    float acc[8] = {};
    const float* wrow = Wt + col * 256;
    for (int k4 = 0; k4 < 64; ++k4) {
        float4 wv = *(const float4*)(wrow + k4 * 4);
#pragma unroll
        for (int m = 0; m < 8; ++m) {
            float4 av = *(const float4*)&hs[g * 8 + m][k4 * 4];
            acc[m] = fmaf(av.x, wv.x, acc[m]);
            acc[m] = fmaf(av.y, wv.y, acc[m]);
            acc[m] = fmaf(av.z, wv.z, acc[m]);
            acc[m] = fmaf(av.w, wv.w, acc[m]);
        }
    }
    float sw = att_s[col], dw = att_d[col];
#pragma unroll
    for (int m = 0; m < 8; ++m) {
        int node = base + g * 8 + m;
        if (node < N) out[(size_t)node * 64 + col] = acc[m];
        float sv = acc[m] * sw, dv = acc[m] * dw;
#pragma unroll
        for (int off = 32; off; off >>= 1) {
            sv += __shfl_xor(sv, off, 64);
            dv += __shfl_xor(dv, off, 64);
        }
        if (col == 0 && node < N) { as_[node] = sv; ad_[node] = dv; }
    }
}

// ------- CSR build over REAL edges only (self-loops handled inline) ----------
__global__ void k_deg(const int* __restrict__ ei, int E, int* __restrict__ deg) {
    for (int i = blockIdx.x * blockDim.x + threadIdx.x; i < E; i += gridDim.x * blockDim.x) {
        atomicAdd(&deg[ei[E + i]], 1);
    }
}

__global__ void k_scan_part(const int* __restrict__ deg, int* __restrict__ out,
                            int* __restrict__ partials, int n) {
    __shared__ int tmp[1024];
    int b = blockIdx.x, t = threadIdx.x;
    int i = b * 1024 + t;
    int v = (i < n) ? deg[i] : 0;
    tmp[t] = v;
    __syncthreads();
    for (int off = 1; off < 1024; off <<= 1) {
        int xval = (t >= off) ? tmp[t - off] : 0;
        __syncthreads();
        tmp[t] += xval;
        __syncthreads();
    }
    if (i < n) out[i] = tmp[t] - v; // exclusive
    if (t == 1023) partials[b] = tmp[t];
}

__global__ void k_scan_small(int* __restrict__ partials, int nblk) {
    int lane = threadIdx.x & 63;
    int carry = 0;
    for (int base = 0; base < nblk; base += 64) {
        int idx = base + lane;
        int v = (idx < nblk) ? partials[idx] : 0;
        int orig = v;
#pragma unroll
        for (int off = 1; off < 64; off <<= 1) {
            int u = __shfl_up(v, off, 64);
            if (lane >= off) v += u;
        }
        if (idx < nblk) partials[idx] = carry + v - orig; // exclusive
        carry += __shfl(v, 63, 64);
    }
}

__global__ void k_scan_add(int* __restrict__ rowptr, const int* __restrict__ partials,
                           int n, int total) {
    int i = blockIdx.x * 1024 + threadIdx.x;
    if (i < n) rowptr[i] += partials[blockIdx.x];
    if (i == 0) rowptr[n] = total;
}

// ---- scatter + fused layer-1 edge weights (full lane-efficiency exp) --------
__global__ void k_scatter(const int* __restrict__ ei, int E,
                          const int* __restrict__ rowptr, int* __restrict__ cursor,
                          const float* __restrict__ as1, const float* __restrict__ ad1,
                          int* __restrict__ csrc, float* __restrict__ wexp) {
    for (int i = blockIdx.x * blockDim.x + threadIdx.x; i < E; i += gridDim.x * blockDim.x) {
        int src = ei[i], dst = ei[E + i];
        int pos = rowptr[dst] + atomicAdd(&cursor[dst], 1);
        csrc[pos] = src;
        float4 a = *(const float4*)(as1 + (size_t)src * 4);
        float4 b = *(const float4*)(ad1 + (size_t)dst * 4);
        float4 w;
        w.x = __expf(lrelu(a.x + b.x));
        w.y = __expf(lrelu(a.y + b.y));
        w.z = __expf(lrelu(a.z + b.z));
        w.w = __expf(lrelu(a.w + b.w));
        *(float4*)(wexp + (size_t)pos * 4) = w;
    }
}

#define EDGE_FMA(W, H)                                              \
    a00 = fmaf(W.x, H.x, a00); a01 = fmaf(W.x, H.y, a01);           \
    a02 = fmaf(W.x, H.z, a02); a03 = fmaf(W.x, H.w, a03);           \
    a10 = fmaf(W.y, H.x, a10); a11 = fmaf(W.y, H.y, a11);           \
    a12 = fmaf(W.y, H.z, a12); a13 = fmaf(W.y, H.w, a13);           \
    a20 = fmaf(W.z, H.x, a20); a21 = fmaf(W.z, H.y, a21);           \
    a22 = fmaf(W.z, H.z, a22); a23 = fmaf(W.z, H.w, a23);           \
    a30 = fmaf(W.w, H.x, a30); a31 = fmaf(W.w, H.y, a31);           \
    a32 = fmaf(W.w, H.z, a32); a33 = fmaf(W.w, H.w, a33);           \
    d0 += W.x; d1 += W.y; d2 += W.z; d3 += W.w;

// --------- GAT layer 1 fused: precomputed wexp4 + h0 agg + W1 GEMM -----------
// Phase 1: 4 dsts/block, 4 slots x 16 lanes, 4-edge ILP (weights preloaded --
// r21 freed the VALU budget; runtime trip count prevents hoist-spill).
// Phase 2: SCALAR W1 + SCALAR LDS -- the only non-spilling, non-slow codegen
// (r4/5/9/19 spills with float4; r11 unroll-1 slow; r13 transposed-agg bank
// conflicts). DO NOT TOUCH PHASE 2.
__global__ void k_gat1f(const float* __restrict__ h0, const float* __restrict__ wexp4,
                        const float* __restrict__ as1, const float* __restrict__ ad1,
                        const int* __restrict__ rowptr, const int* __restrict__ csrc,
                        const float* __restrict__ W1, const float* __restrict__ b1,
                        float* __restrict__ h1out, int N) {
    __shared__ float agg[4][256];
    int t = threadIdx.x, wv = t >> 6, lane = t & 63;
    int slot = lane >> 4, sl = lane & 15;
    int d = blockIdx.x * 4 + wv;
    if (d < N) {
        int s0 = rowptr[d], e0 = rowptr[d + 1];
        float a00=0,a01=0,a02=0,a03=0;
        float a10=0,a11=0,a12=0,a13=0;
        float a20=0,a21=0,a22=0,a23=0;
        float a30=0,a31=0,a32=0,a33=0;
        float d0=0,d1=0,d2=0,d3=0;
        const float* hb = h0 + sl * 4;
        if (slot == 0) {
            // self-loop (weights computed inline, slot 0 only)
            float4 a = *(const float4*)(as1 + (size_t)d * 4);
            float4 b = *(const float4*)(ad1 + (size_t)d * 4);
            float4 w;
            w.x = __expf(lrelu(a.x + b.x));
            w.y = __expf(lrelu(a.y + b.y));
            w.z = __expf(lrelu(a.z + b.z));
            w.w = __expf(lrelu(a.w + b.w));
            float4 hv = *(const float4*)(hb + (size_t)d * 64);
            EDGE_FMA(w, hv);
        }
        int j = s0 + slot;
        for (; j + 12 < e0; j += 16) {
            int sA = csrc[j], sB = csrc[j + 4], sC = csrc[j + 8], sD = csrc[j + 12];
            float4 wA = *(const float4*)(wexp4 + (size_t)j * 4);
            float4 wB = *(const float4*)(wexp4 + (size_t)(j + 4) * 4);
            float4 wC = *(const float4*)(wexp4 + (size_t)(j + 8) * 4);
            float4 wD = *(const float4*)(wexp4 + (size_t)(j + 12) * 4);
            float4 hA = *(const float4*)(hb + (size_t)sA * 64);
            float4 hB = *(const float4*)(hb + (size_t)sB * 64);
            float4 hC = *(const float4*)(hb + (size_t)sC * 64);
            float4 hD = *(const float4*)(hb + (size_t)sD * 64);
            EDGE_FMA(wA, hA);
            EDGE_FMA(wB, hB);
            EDGE_FMA(wC, hC);
            EDGE_FMA(wD, hD);
        }
        for (; j < e0; j += 4) {
            int s = csrc[j];
            float4 w = *(const float4*)(wexp4 + (size_t)j * 4);
            float4 hv = *(const float4*)(hb + (size_t)s * 64);
            EDGE_FMA(w, hv);
        }
#pragma unroll
        for (int off = 16; off <= 32; off <<= 1) {
            a00 += __shfl_xor(a00, off, 64); a01 += __shfl_xor(a01, off, 64);
            a02 += __shfl_xor(a02, off, 64); a03 += __shfl_xor(a03, off, 64);
            a10 += __shfl_xor(a10, off, 64); a11 += __shfl_xor(a11, off, 64);
            a12 += __shfl_xor(a12, off, 64); a13 += __shfl_xor(a13, off, 64);
            a20 += __shfl_xor(a20, off, 64); a21 += __shfl_xor(a21, off, 64);
            a22 += __shfl_xor(a22, off, 64); a23 += __shfl_xor(a23, off, 64);
            a30 += __shfl_xor(a30, off, 64); a31 += __shfl_xor(a31, off, 64);
            a32 += __shfl_xor(a32, off, 64); a33 += __shfl_xor(a33, off, 64);
            d0  += __shfl_xor(d0,  off, 64); d1  += __shfl_xor(d1,  off, 64);
            d2  += __shfl_xor(d2,  off, 64); d3  += __shfl_xor(d3,  off, 64);
        }
        if (slot == 0) {
            float i0 = 1.f / d0, i1 = 1.f / d1, i2 = 1.f / d2, i3 = 1.f / d3;
            *(float4*)&agg[wv][  0 + sl * 4] = make_float4(a00*i0, a01*i0, a02*i0, a03*i0);
            *(float4*)&agg[wv][ 64 + sl * 4] = make_float4(a10*i1, a11*i1, a12*i1, a13*i1);
            *(float4*)&agg[wv][128 + sl * 4] = make_float4(a20*i2, a21*i2, a22*i2, a23*i2);
            *(float4*)&agg[wv][192 + sl * 4] = make_float4(a30*i3, a31*i3, a32*i3, a33*i3);
        }
    }
    __syncthreads();
    int h = t >> 6;
    float o0 = 0.f, o1 = 0.f, o2 = 0.f, o3 = 0.f;
    for (int k = 0; k < 64; ++k) {
        float wv1 = W1[k * 256 + t];
        o0 = fmaf(agg[0][h * 64 + k], wv1, o0);
        o1 = fmaf(agg[1][h * 64 + k], wv1, o1);
        o2 = fmaf(agg[2][h * 64 + k], wv1, o2);
        o3 = fmaf(agg[3][h * 64 + k], wv1, o3);
    }
    float bb = b1[t];
    int base = blockIdx.x * 4;
    if (base + 0 < N) h1out[(size_t)(base + 0) * 256 + t] = fmaxf(o0 + bb, 0.f);
    if (base + 1 < N) h1out[(size_t)(base + 1) * 256 + t] = fmaxf(o1 + bb, 0.f);
    if (base + 2 < N) h1out[(size_t)(base + 2) * 256 + t] = fmaxf(o2 + bb, 0.f);
    if (base + 3 < N) h1out[(size_t)(base + 3) * 256 + t] = fmaxf(o3 + bb, 0.f);
}

// --------- GAT layer 2 (1 head): wave per dst, 2-edge ILP, fused classifier --
__global__ void k_gat2(const float* __restrict__ hlin, const float* __restrict__ as2,
                       const float* __restrict__ ad2, const int* __restrict__ rowptr,
                       const int* __restrict__ csrc, const float* __restrict__ bias,
                       const float* __restrict__ clsW, const float* __restrict__ clsB,
                       float* __restrict__ out, int N) {
    int t = threadIdx.x, wv = t >> 6, lane = t & 63;
    int slot = lane >> 4, sl = lane & 15;
    int d = blockIdx.x * 4 + wv;
    if (d >= N) return;
    int s0 = rowptr[d], e0 = rowptr[d + 1];
    float add = ad2[d];
    float ax = 0.f, ay = 0.f, az = 0.f, aw = 0.f, den = 0.f;
    const float* hb = hlin + sl * 4;
    if (slot == 0) {   // self-loop
        float w = __expf(lrelu(as2[d] + add));
        float4 hv = *(const float4*)(hb + (size_t)d * 64);
        ax = w * hv.x; ay = w * hv.y; az = w * hv.z; aw = w * hv.w;
        den = w;
    }
    int j = s0 + slot;
    for (; j + 4 < e0; j += 8) {
        int sA = csrc[j], sB = csrc[j + 4];
        float wA = __expf(lrelu(as2[sA] + add));
        float wB = __expf(lrelu(as2[sB] + add));
        float4 hA = *(const float4*)(hb + (size_t)sA * 64);
        float4 hB = *(const float4*)(hb + (size_t)sB * 64);
        ax = fmaf(wA, hA.x, ax); ay = fmaf(wA, hA.y, ay);
        az = fmaf(wA, hA.z, az); aw = fmaf(wA, hA.w, aw);
        den += wA;
        ax = fmaf(wB, hB.x, ax); ay = fmaf(wB, hB.y, ay);
        az = fmaf(wB, hB.z, az); aw = fmaf(wB, hB.w, aw);
        den += wB;
    }
    if (j < e0) {
        int s = csrc[j];
        float w = __expf(lrelu(as2[s] + add));
        float4 hv = *(const float4*)(hb + (size_t)s * 64);
        ax = fmaf(w, hv.x, ax); ay = fmaf(w, hv.y, ay);
        az = fmaf(w, hv.z, az); aw = fmaf(w, hv.w, aw);
        den += w;
    }
#pragma unroll
    for (int off = 16; off <= 32; off <<= 1) {
        ax += __shfl_xor(ax, off, 64); ay += __shfl_xor(ay, off, 64);
        az += __shfl_xor(az, off, 64); aw += __shfl_xor(aw, off, 64);
        den += __shfl_xor(den, off, 64);
    }
    float inv = 1.f / den;
    float4 bb = *(const float4*)(bias + sl * 4);
    float4 cw = *(const float4*)(clsW + sl * 4);
    float p = fmaxf(fmaf(ax, inv, bb.x), 0.f) * cw.x
            + fmaxf(fmaf(ay, inv, bb.y), 0.f) * cw.y
            + fmaxf(fmaf(az, inv, bb.z), 0.f) * cw.z
            + fmaxf(fmaf(aw, inv, bb.w), 0.f) * cw.w;
#pragma unroll
    for (int off = 1; off <= 8; off <<= 1) p += __shfl_xor(p, off, 64);
    if (lane == 0) out[d] = p + clsB[0];
}

extern "C" void kernel_launch(void* const* d_in, const int* in_sizes, int n_in,
                              void* d_out, int out_size, void* d_ws, size_t ws_size,
                              hipStream_t stream) {
    const float* x     = (const float*)d_in[0];
    const int*   ei    = (const int*)d_in[1];
    const float* projW = (const float*)d_in[2];
    const float* projB = (const float*)d_in[3];
    const float* W1    = (const float*)d_in[4];
    const float* as1w  = (const float*)d_in[5];
    const float* ad1w  = (const float*)d_in[6];
    const float* b1    = (const float*)d_in[7];
    const float* W2    = (const float*)d_in[8];
    const float* as2w  = (const float*)d_in[9];
    const float* ad2w  = (const float*)d_in[10];
    const float* b2    = (const float*)d_in[11];
    const float* clsW  = (const float*)d_in[12];
    const float* clsB  = (const float*)d_in[13];
    float* out = (float*)d_out;

    const int N = in_sizes[0] / F_IN;
    const int E = in_sizes[1] / 2;

    char* ws = (char*)d_ws;
    size_t off = 0;
    auto alloc = [&](size_t bytes) -> void* {
        void* p = ws + off;
        off += (bytes + 255) & ~(size_t)255;
        return p;
    };
    float* h0     = (float*)alloc((size_t)N * 64 * 4);   // reused as h2lin
    float* h1     = (float*)alloc((size_t)N * 256 * 4);
    float* as1    = (float*)alloc((size_t)N * 4 * 4);
    float* ad1    = (float*)alloc((size_t)N * 4 * 4);
    float* as2    = (float*)alloc((size_t)N * 4);
    float* ad2    = (float*)alloc((size_t)N * 4);
    int*   dc     = (int*)alloc((size_t)2 * N * 4);      // deg | cursor adjacent
    int*   deg    = dc;
    int*   cursor = dc + N;
    int*   rowptr = (int*)alloc((size_t)(N + 1) * 4);
    int*   parts  = (int*)alloc(1024 * 4);
    int*   csrc   = (int*)alloc((size_t)E * 4);
    float* wexp1  = (float*)alloc((size_t)E * 4 * 4);
    float* wt0    = (float*)alloc(64 * KP_PROJ * 4);
    float* wt2    = (float*)alloc(64 * 256 * 4);
    float* va     = (float*)alloc(512 * 4);
    float* h2lin  = h0;

    // weight transposes + va vectors + deg/cursor zeroing (one dispatch)
    const int ntr = 64 * KP_PROJ + 64 * 256 + 512 + 2 * N;
    k_trans<<<(ntr + 255) / 256, 256, 0, stream>>>(
        projW, W2, W1, as1w, ad1w, wt0, wt2, va, dc, 2 * N);

    // degree + row offsets
    k_deg<<<1024, 256, 0, stream>>>(ei, E, deg);
    int nblk = (N + 1023) / 1024;
    k_scan_part<<<nblk, 1024, 0, stream>>>(deg, rowptr, parts, N);
    k_scan_small<<<1, 64, 0, stream>>>(parts, nblk);
    k_scan_add<<<nblk, 1024, 0, stream>>>(rowptr, parts, N, E);

    // MLP in (+ fused as1/ad1 reduction) -- before scatter, which needs as1/ad1
    k_proj<<<(N + 31) / 32, 256, 0, stream>>>(x, wt0, projB, va, h0, as1, ad1, N);

    // scatter + fused layer-1 edge weights
    k_scatter<<<1024, 256, 0, stream>>>(ei, E, rowptr, cursor, as1, ad1, csrc, wexp1);

    // GAT layer 1 (h0-domain aggregation, precomputed weights, 4 dst/block)
    k_gat1f<<<(N + 3) / 4, 256, 0, stream>>>(h0, wexp1, as1, ad1, rowptr, csrc,
                                             W1, b1, h1, N);

    // GAT layer 2 + classifier (edge weights fused into k_gat2)
    k_lin2<<<(N + 31) / 32, 256, 0, stream>>>(h1, wt2, as2w, ad2w, h2lin, as2, ad2, N);
    k_gat2<<<(N + 3) / 4, 256, 0, stream>>>(h2lin, as2, ad2, rowptr, csrc, b2,
                                            clsW, clsB, out, N);
}

// Round 23
// 301.773 us; speedup vs baseline: 1.0148x; 1.0148x over previous
//
#include <hip/hip_runtime.h>

#define F_IN 165
#define KP_PROJ 168
constexpr float NEG_SLOPE = 0.2f;

// lrelu(z) = max(z, 0.2z) -- 2 VALU inst vs 3 for cmp/cndmask form.
__device__ __forceinline__ float lrelu(float z) { return fmaxf(z, NEG_SLOPE * z); }

// ---- weight transposes + va vectors + workspace zeroing ---------------------
__global__ void k_trans(const float* __restrict__ pw, const float* __restrict__ w2,
                        const float* __restrict__ w1, const float* __restrict__ as1w,
                        const float* __restrict__ ad1w,
                        float* __restrict__ t0, float* __restrict__ t2,
                        float* __restrict__ va, int* __restrict__ dc, int ndc) {
    int i = blockIdx.x * 256 + threadIdx.x;
    const int n0 = 64 * KP_PROJ, n2 = 64 * 256;
    if (i < n0) {
        int c = i / KP_PROJ, r = i - c * KP_PROJ;
        t0[i] = (r < F_IN) ? pw[r * 64 + c] : 0.f;
    } else if (i < n0 + n2) {
        int j = i - n0; int c = j >> 8, r = j & 255;
        t2[j] = w2[r * 64 + c];
    } else if (i < n0 + n2 + 512) {
        int j = i - n0 - n2;          // 0..511
        int i2 = j >> 6;              // 0..7 = plane*4 + h
        int plane = i2 >> 2, h = i2 & 3, k = j & 63;
        const float* att = plane ? ad1w : as1w;
        float acc = 0.f;
        for (int c = 0; c < 64; ++c)
            acc = fmaf(w1[k * 256 + h * 64 + c], att[h * 64 + c], acc);
        va[j] = acc;
    }
    int z = i - (n0 + n2 + 512);
    if (z >= 0 && z < ndc) dc[z] = 0;
}

// ---- h0 = relu(x @ W + b) + fused as1/ad1 via single-wave LDS transpose -----
__global__ void k_proj(const float* __restrict__ x, const float* __restrict__ Wt,
                       const float* __restrict__ b, const float* __restrict__ va,
                       float* __restrict__ h0, float* __restrict__ as_,
                       float* __restrict__ ad_, int N) {
    __shared__ float xs[32][KP_PROJ];
    __shared__ float vas[8][65];
    __shared__ float hrow[4][64];
    int base = blockIdx.x * 32;
    int t = threadIdx.x;
    for (int idx = t; idx < 512; idx += 256)
        vas[idx >> 6][idx & 63] = va[idx];
    for (int idx = t; idx < 32 * KP_PROJ; idx += 256) {
        int nl = idx / KP_PROJ, k = idx - nl * KP_PROJ;
        int node = base + nl;
        xs[nl][k] = (node < N && k < F_IN) ? x[(size_t)node * F_IN + k] : 0.f;
    }
    __syncthreads();
    int g = t >> 6, col = t & 63;
    float acc[8];
    float bb = b[col];
#pragma unroll
    for (int m = 0; m < 8; ++m) acc[m] = bb;
    const float* wrow = Wt + col * KP_PROJ;
    for (int k4 = 0; k4 < KP_PROJ / 4; ++k4) {
        float4 wv = *(const float4*)(wrow + k4 * 4);
#pragma unroll
        for (int m = 0; m < 8; ++m) {
            float4 av = *(const float4*)&xs[g * 8 + m][k4 * 4];
            acc[m] = fmaf(av.x, wv.x, acc[m]);
            acc[m] = fmaf(av.y, wv.y, acc[m]);
            acc[m] = fmaf(av.z, wv.z, acc[m]);
            acc[m] = fmaf(av.w, wv.w, acc[m]);
        }
    }
    int i8 = col & 7, c8 = col >> 3;
    const float* vbase = &vas[i8][c8 * 8];
    const float* hbase = &hrow[g][c8 * 8];
#pragma unroll
    for (int m = 0; m < 8; ++m) {
        int node = base + g * 8 + m;
        float h = fmaxf(acc[m], 0.f);
        if (node < N) h0[(size_t)node * 64 + col] = h;
        hrow[g][col] = h;            // wave-private LDS, wave-synchronous use
        float r = 0.f;
#pragma unroll
        for (int e = 0; e < 8; ++e)
            r = fmaf(hbase[e], vbase[e], r);
        r += __shfl_xor(r, 8, 64);
        r += __shfl_xor(r, 16, 64);
        r += __shfl_xor(r, 32, 64);
        if (node < N && col < 8) {
            if (col < 4) as_[(size_t)node * 4 + col] = r;
            else         ad_[(size_t)node * 4 + (col - 4)] = r;
        }
    }
}

// ---- h2lin = h1 @ W2: Wt2[64][256], 32 nodes/block, 4 groups x 8, fused att -
__global__ void k_lin2(const float* __restrict__ h1, const float* __restrict__ Wt,
                       const float* __restrict__ att_s, const float* __restrict__ att_d,
                       float* __restrict__ out, float* __restrict__ as_,
                       float* __restrict__ ad_, int N) {
    __shared__ float hs[32][256];
    int base = blockIdx.x * 32;
    int t = threadIdx.x;
    for (int i = 0; i < 8; ++i) {
        int idx4 = t + i * 256;
        int nl = idx4 >> 6, k4 = idx4 & 63;
        int node = base + nl;
        float4 v = make_float4(0.f, 0.f, 0.f, 0.f);
        if (node < N) v = *(const float4*)(h1 + (size_t)node * 256 + k4 * 4);
        *(float4*)&hs[nl][k4 * 4] = v;
    }
    __syncthreads();
    int g = t >> 6, col = t & 63;
    float acc[8] = {};
    const float* wrow = Wt + col * 256;
    for (int k4 = 0; k4 < 64; ++k4) {
        float4 wv = *(const float4*)(wrow + k4 * 4);
#pragma unroll
        for (int m = 0; m < 8; ++m) {
            float4 av = *(const float4*)&hs[g * 8 + m][k4 * 4];
            acc[m] = fmaf(av.x, wv.x, acc[m]);
            acc[m] = fmaf(av.y, wv.y, acc[m]);
            acc[m] = fmaf(av.z, wv.z, acc[m]);
            acc[m] = fmaf(av.w, wv.w, acc[m]);
        }
    }
    float sw = att_s[col], dw = att_d[col];
#pragma unroll
    for (int m = 0; m < 8; ++m) {
        int node = base + g * 8 + m;
        if (node < N) out[(size_t)node * 64 + col] = acc[m];
        float sv = acc[m] * sw, dv = acc[m] * dw;
#pragma unroll
        for (int off = 32; off; off >>= 1) {
            sv += __shfl_xor(sv, off, 64);
            dv += __shfl_xor(dv, off, 64);
        }
        if (col == 0 && node < N) { as_[node] = sv; ad_[node] = dv; }
    }
}

// ------- CSR build over REAL edges only (self-loops handled inline) ----------
__global__ void k_deg(const int* __restrict__ ei, int E, int* __restrict__ deg) {
    for (int i = blockIdx.x * blockDim.x + threadIdx.x; i < E; i += gridDim.x * blockDim.x) {
        atomicAdd(&deg[ei[E + i]], 1);
    }
}

__global__ void k_scan_part(const int* __restrict__ deg, int* __restrict__ out,
                            int* __restrict__ partials, int n) {
    __shared__ int tmp[1024];
    int b = blockIdx.x, t = threadIdx.x;
    int i = b * 1024 + t;
    int v = (i < n) ? deg[i] : 0;
    tmp[t] = v;
    __syncthreads();
    for (int off = 1; off < 1024; off <<= 1) {
        int xval = (t >= off) ? tmp[t - off] : 0;
        __syncthreads();
        tmp[t] += xval;
        __syncthreads();
    }
    if (i < n) out[i] = tmp[t] - v; // exclusive
    if (t == 1023) partials[b] = tmp[t];
}

__global__ void k_scan_small(int* __restrict__ partials, int nblk) {
    int lane = threadIdx.x & 63;
    int carry = 0;
    for (int base = 0; base < nblk; base += 64) {
        int idx = base + lane;
        int v = (idx < nblk) ? partials[idx] : 0;
        int orig = v;
#pragma unroll
        for (int off = 1; off < 64; off <<= 1) {
            int u = __shfl_up(v, off, 64);
            if (lane >= off) v += u;
        }
        if (idx < nblk) partials[idx] = carry + v - orig; // exclusive
        carry += __shfl(v, 63, 64);
    }
}

__global__ void k_scan_add(int* __restrict__ rowptr, const int* __restrict__ partials,
                           int n, int total) {
    int i = blockIdx.x * 1024 + threadIdx.x;
    if (i < n) rowptr[i] += partials[blockIdx.x];
    if (i == 0) rowptr[n] = total;
}

// ---- scatter + fused layer-1 edge weights (full lane-efficiency exp) --------
__global__ void k_scatter(const int* __restrict__ ei, int E,
                          const int* __restrict__ rowptr, int* __restrict__ cursor,
                          const float* __restrict__ as1, const float* __restrict__ ad1,
                          int* __restrict__ csrc, float* __restrict__ wexp) {
    for (int i = blockIdx.x * blockDim.x + threadIdx.x; i < E; i += gridDim.x * blockDim.x) {
        int src = ei[i], dst = ei[E + i];
        int pos = rowptr[dst] + atomicAdd(&cursor[dst], 1);
        csrc[pos] = src;
        float4 a = *(const float4*)(as1 + (size_t)src * 4);
        float4 b = *(const float4*)(ad1 + (size_t)dst * 4);
        float4 w;
        w.x = __expf(lrelu(a.x + b.x));
        w.y = __expf(lrelu(a.y + b.y));
        w.z = __expf(lrelu(a.z + b.z));
        w.w = __expf(lrelu(a.w + b.w));
        *(float4*)(wexp + (size_t)pos * 4) = w;
    }
}

#define EDGE_FMA(W, H)                                              \
    a00 = fmaf(W.x, H.x, a00); a01 = fmaf(W.x, H.y, a01);           \
    a02 = fmaf(W.x, H.z, a02); a03 = fmaf(W.x, H.w, a03);           \
    a10 = fmaf(W.y, H.x, a10); a11 = fmaf(W.y, H.y, a11);           \
    a12 = fmaf(W.y, H.z, a12); a13 = fmaf(W.y, H.w, a13);           \
    a20 = fmaf(W.z, H.x, a20); a21 = fmaf(W.z, H.y, a21);           \
    a22 = fmaf(W.z, H.z, a22); a23 = fmaf(W.z, H.w, a23);           \
    a30 = fmaf(W.w, H.x, a30); a31 = fmaf(W.w, H.y, a31);           \
    a32 = fmaf(W.w, H.z, a32); a33 = fmaf(W.w, H.w, a33);           \
    d0 += W.x; d1 += W.y; d2 += W.z; d3 += W.w;

// --------- GAT layer 1 fused: precomputed wexp4 + h0 agg + W1 GEMM -----------
// Phase 1: 4 dsts/block, 4 slots x 16 lanes, 2-edge ILP (r21 optimum; r22's
// 4-edge ILP cost occupancy via VGPR 36 and regressed -- depth 2 matches the
// avg 4.3 edges/slot). Weights preloaded from wexp4 (slot-uniform broadcast).
// Phase 2: SCALAR W1 + SCALAR LDS -- the only non-spilling, non-slow codegen
// (r4/5/9/19 spills with float4; r11 unroll-1 slow; r13 transposed-agg bank
// conflicts). DO NOT TOUCH.
__global__ void k_gat1f(const float* __restrict__ h0, const float* __restrict__ wexp4,
                        const float* __restrict__ as1, const float* __restrict__ ad1,
                        const int* __restrict__ rowptr, const int* __restrict__ csrc,
                        const float* __restrict__ W1, const float* __restrict__ b1,
                        float* __restrict__ h1out, int N) {
    __shared__ float agg[4][256];
    int t = threadIdx.x, wv = t >> 6, lane = t & 63;
    int slot = lane >> 4, sl = lane & 15;
    int d = blockIdx.x * 4 + wv;
    if (d < N) {
        int s0 = rowptr[d], e0 = rowptr[d + 1];
        float a00=0,a01=0,a02=0,a03=0;
        float a10=0,a11=0,a12=0,a13=0;
        float a20=0,a21=0,a22=0,a23=0;
        float a30=0,a31=0,a32=0,a33=0;
        float d0=0,d1=0,d2=0,d3=0;
        const float* hb = h0 + sl * 4;
        if (slot == 0) {
            // self-loop (weights computed inline, slot 0 only)
            float4 a = *(const float4*)(as1 + (size_t)d * 4);
            float4 b = *(const float4*)(ad1 + (size_t)d * 4);
            float4 w;
            w.x = __expf(lrelu(a.x + b.x));
            w.y = __expf(lrelu(a.y + b.y));
            w.z = __expf(lrelu(a.z + b.z));
            w.w = __expf(lrelu(a.w + b.w));
            float4 hv = *(const float4*)(hb + (size_t)d * 64);
            EDGE_FMA(w, hv);
        }
        int j = s0 + slot;
        for (; j + 4 < e0; j += 8) {
            int sA = csrc[j], sB = csrc[j + 4];
            float4 wA = *(const float4*)(wexp4 + (size_t)j * 4);
            float4 wB = *(const float4*)(wexp4 + (size_t)(j + 4) * 4);
            float4 hA = *(const float4*)(hb + (size_t)sA * 64);
            float4 hB = *(const float4*)(hb + (size_t)sB * 64);
            EDGE_FMA(wA, hA);
            EDGE_FMA(wB, hB);
        }
        if (j < e0) {
            int s = csrc[j];
            float4 w = *(const float4*)(wexp4 + (size_t)j * 4);
            float4 hv = *(const float4*)(hb + (size_t)s * 64);
            EDGE_FMA(w, hv);
        }
#pragma unroll
        for (int off = 16; off <= 32; off <<= 1) {
            a00 += __shfl_xor(a00, off, 64); a01 += __shfl_xor(a01, off, 64);
            a02 += __shfl_xor(a02, off, 64); a03 += __shfl_xor(a03, off, 64);
            a10 += __shfl_xor(a10, off, 64); a11 += __shfl_xor(a11, off, 64);
            a12 += __shfl_xor(a12, off, 64); a13 += __shfl_xor(a13, off, 64);
            a20 += __shfl_xor(a20, off, 64); a21 += __shfl_xor(a21, off, 64);
            a22 += __shfl_xor(a22, off, 64); a23 += __shfl_xor(a23, off, 64);
            a30 += __shfl_xor(a30, off, 64); a31 += __shfl_xor(a31, off, 64);
            a32 += __shfl_xor(a32, off, 64); a33 += __shfl_xor(a33, off, 64);
            d0  += __shfl_xor(d0,  off, 64); d1  += __shfl_xor(d1,  off, 64);
            d2  += __shfl_xor(d2,  off, 64); d3  += __shfl_xor(d3,  off, 64);
        }
        if (slot == 0) {
            float i0 = 1.f / d0, i1 = 1.f / d1, i2 = 1.f / d2, i3 = 1.f / d3;
            *(float4*)&agg[wv][  0 + sl * 4] = make_float4(a00*i0, a01*i0, a02*i0, a03*i0);
            *(float4*)&agg[wv][ 64 + sl * 4] = make_float4(a10*i1, a11*i1, a12*i1, a13*i1);
            *(float4*)&agg[wv][128 + sl * 4] = make_float4(a20*i2, a21*i2, a22*i2, a23*i2);
            *(float4*)&agg[wv][192 + sl * 4] = make_float4(a30*i3, a31*i3, a32*i3, a33*i3);
        }
    }
    __syncthreads();
    int h = t >> 6;
    float o0 = 0.f, o1 = 0.f, o2 = 0.f, o3 = 0.f;
    for (int k = 0; k < 64; ++k) {
        float wv1 = W1[k * 256 + t];
        o0 = fmaf(agg[0][h * 64 + k], wv1, o0);
        o1 = fmaf(agg[1][h * 64 + k], wv1, o1);
        o2 = fmaf(agg[2][h * 64 + k], wv1, o2);
        o3 = fmaf(agg[3][h * 64 + k], wv1, o3);
    }
    float bb = b1[t];
    int base = blockIdx.x * 4;
    if (base + 0 < N) h1out[(size_t)(base + 0) * 256 + t] = fmaxf(o0 + bb, 0.f);
    if (base + 1 < N) h1out[(size_t)(base + 1) * 256 + t] = fmaxf(o1 + bb, 0.f);
    if (base + 2 < N) h1out[(size_t)(base + 2) * 256 + t] = fmaxf(o2 + bb, 0.f);
    if (base + 3 < N) h1out[(size_t)(base + 3) * 256 + t] = fmaxf(o3 + bb, 0.f);
}

// --------- GAT layer 2 (1 head): wave per dst, 2-edge ILP, fused classifier --
__global__ void k_gat2(const float* __restrict__ hlin, const float* __restrict__ as2,
                       const float* __restrict__ ad2, const int* __restrict__ rowptr,
                       const int* __restrict__ csrc, const float* __restrict__ bias,
                       const float* __restrict__ clsW, const float* __restrict__ clsB,
                       float* __restrict__ out, int N) {
    int t = threadIdx.x, wv = t >> 6, lane = t & 63;
    int slot = lane >> 4, sl = lane & 15;
    int d = blockIdx.x * 4 + wv;
    if (d >= N) return;
    int s0 = rowptr[d], e0 = rowptr[d + 1];
    float add = ad2[d];
    float ax = 0.f, ay = 0.f, az = 0.f, aw = 0.f, den = 0.f;
    const float* hb = hlin + sl * 4;
    if (slot == 0) {   // self-loop
        float w = __expf(lrelu(as2[d] + add));
        float4 hv = *(const float4*)(hb + (size_t)d * 64);
        ax = w * hv.x; ay = w * hv.y; az = w * hv.z; aw = w * hv.w;
        den = w;
    }
    int j = s0 + slot;
    for (; j + 4 < e0; j += 8) {
        int sA = csrc[j], sB = csrc[j + 4];
        float wA = __expf(lrelu(as2[sA] + add));
        float wB = __expf(lrelu(as2[sB] + add));
        float4 hA = *(const float4*)(hb + (size_t)sA * 64);
        float4 hB = *(const float4*)(hb + (size_t)sB * 64);
        ax = fmaf(wA, hA.x, ax); ay = fmaf(wA, hA.y, ay);
        az = fmaf(wA, hA.z, az); aw = fmaf(wA, hA.w, aw);
        den += wA;
        ax = fmaf(wB, hB.x, ax); ay = fmaf(wB, hB.y, ay);
        az = fmaf(wB, hB.z, az); aw = fmaf(wB, hB.w, aw);
        den += wB;
    }
    if (j < e0) {
        int s = csrc[j];
        float w = __expf(lrelu(as2[s] + add));
        float4 hv = *(const float4*)(hb + (size_t)s * 64);
        ax = fmaf(w, hv.x, ax); ay = fmaf(w, hv.y, ay);
        az = fmaf(w, hv.z, az); aw = fmaf(w, hv.w, aw);
        den += w;
    }
#pragma unroll
    for (int off = 16; off <= 32; off <<= 1) {
        ax += __shfl_xor(ax, off, 64); ay += __shfl_xor(ay, off, 64);
        az += __shfl_xor(az, off, 64); aw += __shfl_xor(aw, off, 64);
        den += __shfl_xor(den, off, 64);
    }
    float inv = 1.f / den;
    float4 bb = *(const float4*)(bias + sl * 4);
    float4 cw = *(const float4*)(clsW + sl * 4);
    float p = fmaxf(fmaf(ax, inv, bb.x), 0.f) * cw.x
            + fmaxf(fmaf(ay, inv, bb.y), 0.f) * cw.y
            + fmaxf(fmaf(az, inv, bb.z), 0.f) * cw.z
            + fmaxf(fmaf(aw, inv, bb.w), 0.f) * cw.w;
#pragma unroll
    for (int off = 1; off <= 8; off <<= 1) p += __shfl_xor(p, off, 64);
    if (lane == 0) out[d] = p + clsB[0];
}

extern "C" void kernel_launch(void* const* d_in, const int* in_sizes, int n_in,
                              void* d_out, int out_size, void* d_ws, size_t ws_size,
                              hipStream_t stream) {
    const float* x     = (const float*)d_in[0];
    const int*   ei    = (const int*)d_in[1];
    const float* projW = (const float*)d_in[2];
    const float* projB = (const float*)d_in[3];
    const float* W1    = (const float*)d_in[4];
    const float* as1w  = (const float*)d_in[5];
    const float* ad1w  = (const float*)d_in[6];
    const float* b1    = (const float*)d_in[7];
    const float* W2    = (const float*)d_in[8];
    const float* as2w  = (const float*)d_in[9];
    const float* ad2w  = (const float*)d_in[10];
    const float* b2    = (const float*)d_in[11];
    const float* clsW  = (const float*)d_in[12];
    const float* clsB  = (const float*)d_in[13];
    float* out = (float*)d_out;

    const int N = in_sizes[0] / F_IN;
    const int E = in_sizes[1] / 2;

    char* ws = (char*)d_ws;
    size_t off = 0;
    auto alloc = [&](size_t bytes) -> void* {
        void* p = ws + off;
        off += (bytes + 255) & ~(size_t)255;
        return p;
    };
    float* h0     = (float*)alloc((size_t)N * 64 * 4);   // reused as h2lin
    float* h1     = (float*)alloc((size_t)N * 256 * 4);
    float* as1    = (float*)alloc((size_t)N * 4 * 4);
    float* ad1    = (float*)alloc((size_t)N * 4 * 4);
    float* as2    = (float*)alloc((size_t)N * 4);
    float* ad2    = (float*)alloc((size_t)N * 4);
    int*   dc     = (int*)alloc((size_t)2 * N * 4);      // deg | cursor adjacent
    int*   deg    = dc;
    int*   cursor = dc + N;
    int*   rowptr = (int*)alloc((size_t)(N + 1) * 4);
    int*   parts  = (int*)alloc(1024 * 4);
    int*   csrc   = (int*)alloc((size_t)E * 4);
    float* wexp1  = (float*)alloc((size_t)E * 4 * 4);
    float* wt0    = (float*)alloc(64 * KP_PROJ * 4);
    float* wt2    = (float*)alloc(64 * 256 * 4);
    float* va     = (float*)alloc(512 * 4);
    float* h2lin  = h0;

    // weight transposes + va vectors + deg/cursor zeroing (one dispatch)
    const int ntr = 64 * KP_PROJ + 64 * 256 + 512 + 2 * N;
    k_trans<<<(ntr + 255) / 256, 256, 0, stream>>>(
        projW, W2, W1, as1w, ad1w, wt0, wt2, va, dc, 2 * N);

    // degree + row offsets
    k_deg<<<1024, 256, 0, stream>>>(ei, E, deg);
    int nblk = (N + 1023) / 1024;
    k_scan_part<<<nblk, 1024, 0, stream>>>(deg, rowptr, parts, N);
    k_scan_small<<<1, 64, 0, stream>>>(parts, nblk);
    k_scan_add<<<nblk, 1024, 0, stream>>>(rowptr, parts, N, E);

    // MLP in (+ fused as1/ad1 reduction) -- before scatter, which needs as1/ad1
    k_proj<<<(N + 31) / 32, 256, 0, stream>>>(x, wt0, projB, va, h0, as1, ad1, N);

    // scatter + fused layer-1 edge weights
    k_scatter<<<1024, 256, 0, stream>>>(ei, E, rowptr, cursor, as1, ad1, csrc, wexp1);

    // GAT layer 1 (h0-domain aggregation, precomputed weights, 4 dst/block)
    k_gat1f<<<(N + 3) / 4, 256, 0, stream>>>(h0, wexp1, as1, ad1, rowptr, csrc,
                                             W1, b1, h1, N);

    // GAT layer 2 + classifier (edge weights fused into k_gat2)
    k_lin2<<<(N + 31) / 32, 256, 0, stream>>>(h1, wt2, as2w, ad2w, h2lin, as2, ad2, N);
    k_gat2<<<(N + 3) / 4, 256, 0, stream>>>(h2lin, as2, ad2, rowptr, csrc, b2,
                                            clsW, clsB, out, N);
}